// Round 7
// baseline (321.180 us; speedup 1.0000x reference)
//
#include <hip/hip_runtime.h>
#include <cstdint>
#include <cstddef>

// ---------------------------------------------------------------------------
// Problem constants (LEVEL=16, LENGTH=64, TOPK=2, SIZE=512, BATCH=32)
// Cheap path: f16 MFMA scores; rows with cheap top-2/3 gaps < DELTA=0.25 get
// exact f32 refinement over candidates {z: cheap[z] >= cheap_top2 - DELTA}.
//
// K1 history:
// r7:  64m x 512n, DMA-staged, 2-barrier, conflicted: 98us.
// r8/r9: fragment-order LDS (conflicts 7.4M->0): 122us.
// r10: LDS dbuf + __syncthreads: 122us (barrier drains vmcnt(0) each step).
// r11: no-LDS direct (scattered B sources, acc=128 regs): 146us.
// r12: split-N, acc=64, 3 blocks/CU: 120us (occupancy 2x'd, time unchanged).
// r13: packed-P contiguous DMA bursts + BK=64: 91us, conflicts 0, but
//     staging still ~13 B/cy/CU. Root cause finally isolated: we push 578MB
//     through global_load_lds, 462MB of it the SAME 512KB B staged by all
//     1808 blocks. DMA-pipe volume, not source pattern, is the floor.
// r14: B is never staged. Wave reads B fragments DIRECT from packed P
//     (contiguous 1KB/instruction, L2-resident; ~1.8MB/CU total) into regs.
//     Only A (8KB/step, must be wave-shared) goes through LDS: reg-staged
//     f32->f16, double-buffered (2x8KB), ONE barrier/step, next-step A
//     loads hoisted above compute so HBM latency hides under MFMA.
//     LDS-staged volume 578MB -> 59MB.
// ---------------------------------------------------------------------------
#define B_DIM   32
#define L_DIM   48
#define NCELLS  904
#define SZ      512
#define NEGF    (-1e8f)
#define DELTA   0.25f
#define MAXC    32          // max candidates per row kept (z-ascending)

// d_out layout (f32), outputs concatenated flat in return order
#define OFF_S   1572864
#define OFF_N   1575936
#define OFF_L   1579008
#define OFF_R   1582080

typedef _Float16  f16x8 __attribute__((ext_vector_type(8)));
typedef float     f32x4 __attribute__((ext_vector_type(4)));

static __device__ __forceinline__ uint16_t f2bf(float f) {
    uint32_t u = __builtin_bit_cast(uint32_t, f);
    u += 0x7fffu + ((u >> 16) & 1u);
    return (uint16_t)(u >> 16);
}

#define GLD16(gp, lp) __builtin_amdgcn_global_load_lds(                        \
        (__attribute__((address_space(1))) void*)(gp),                         \
        (__attribute__((address_space(3))) void*)(lp), 16, 0, 0)

static __device__ __forceinline__ int level_off(int n) {
    return n * 64 - (n * (n - 1)) / 2;
}

// ---------------------------------------------------------------------------
// P0: pack mat into fragment-chunk order, f16(64*mat).
// Chunk c = ksub*32 + q (ksub=k/32 in 0..15, q=n/16 in 0..31), 1KB each:
//   P[c*512 + lane*8 + j] = f16(64 * mat[16q + (lane&15)][32*ksub + (lane>>4)*8 + j])
// A wave reading P + c*512 + lane*8 gets fragment (q, ksub) lane-linear as
// one contiguous, fully-coalesced 1KB transaction.
// ---------------------------------------------------------------------------
__global__ __launch_bounds__(256)
void prep_mat(const float* __restrict__ mat, _Float16* __restrict__ P)
{
    const int tg   = blockIdx.x * 256 + threadIdx.x;   // 0..32767
    const int c    = tg >> 6, lane = tg & 63;
    const int srow = 16 * (c & 31) + (lane & 15);
    const int scol = 32 * (c >> 5) + (lane >> 4) * 8;
    const float4 a = *(const float4*)(mat + (size_t)srow * 512 + scol);
    const float4 b = *(const float4*)(mat + (size_t)srow * 512 + scol + 4);
    f16x8 w;
    w[0]=(_Float16)(a.x*64.f); w[1]=(_Float16)(a.y*64.f);
    w[2]=(_Float16)(a.z*64.f); w[3]=(_Float16)(a.w*64.f);
    w[4]=(_Float16)(b.x*64.f); w[5]=(_Float16)(b.y*64.f);
    w[6]=(_Float16)(b.z*64.f); w[7]=(_Float16)(b.w*64.f);
    *(f16x8*)(P + (size_t)tg * 8) = w;
}

// ---------------------------------------------------------------------------
// K1: T'[m,e] = sum_d f16(16*A[m,d]) * f16(64*mat[e,d]).  Grid (2,904):
// x = n-half (256 cols), y = m-tile (64 rows). BK=64, 8 K-steps (k-order
// staggered per block; accumulation order only). 4 waves; wave w owns
// n-range n0+64w..+64, acc[4][4]. T' is 1024x the true value.
//
// r14 structure (one barrier per step):
//   As16[2][8*512] f16 double-buffer; chunk (kki*4+mi) = A fragment
//   (rows m0+mi*16..+16, k kki*32..+32), lane-linear both sides.
//   Thread (w,lane) stages chunks 2w, 2w+1: two f32x4 loads -> x16 -> f16
//   -> ds_write_b128. Next-step loads are issued BEFORE the compute phase.
//   B fragments load direct from P into regs (no LDS, no DMA).
// ---------------------------------------------------------------------------
__global__ __launch_bounds__(256, 3)
void gemm_fused(const float* __restrict__ A,        // chart_h f32 [57856][512]
                const _Float16* __restrict__ P,     // packed mat16, 512 chunks
                _Float16* __restrict__ C)           // T16 [57856][512]
{
    __shared__ _Float16 As16[2][8 * 512];    // 2 x 8 KB

    const int t = threadIdx.x;
    const int wave = t >> 6, lane = t & 63;
    const int n0 = blockIdx.x * 256;
    const int nq = n0 >> 4;                  // 0 or 16
    const int m0 = blockIdx.y * 64;
    const int col_l = lane & 15, quad = lane >> 4;
    const int stag = blockIdx.y & 7;

    f32x4 acc[4][4];
#pragma unroll
    for (int i = 0; i < 4; ++i)
#pragma unroll
        for (int j = 0; j < 4; ++j) acc[i][j] = (f32x4){0.f, 0.f, 0.f, 0.f};

    // A staging bases for this thread's two chunks (c = wave*2 + h):
    //   chunk c: kki = c>>2, mi = c&3; row m0+mi*16+col_l, k kki*32+quad*8
    const int c0 = wave * 2, c1 = wave * 2 + 1;
    const float* ab0 = A + (size_t)(m0 + (c0 & 3) * 16 + col_l) * 512
                         + (c0 >> 2) * 32 + quad * 8;
    const float* ab1 = A + (size_t)(m0 + (c1 & 3) * 16 + col_l) * 512
                         + (c1 >> 2) * 32 + quad * 8;

    // prologue: stage step 0 into buffer 0
    {
        const int kse = stag;
        const f32x4 q0a = *(const f32x4*)(ab0 + kse * 64);
        const f32x4 q0b = *(const f32x4*)(ab0 + kse * 64 + 4);
        const f32x4 q1a = *(const f32x4*)(ab1 + kse * 64);
        const f32x4 q1b = *(const f32x4*)(ab1 + kse * 64 + 4);
        f16x8 av0, av1;
#pragma unroll
        for (int j = 0; j < 4; ++j) {
            av0[j] = (_Float16)(q0a[j] * 16.f); av0[j + 4] = (_Float16)(q0b[j] * 16.f);
            av1[j] = (_Float16)(q1a[j] * 16.f); av1[j + 4] = (_Float16)(q1b[j] * 16.f);
        }
        *(f16x8*)&As16[0][c0 * 512 + lane * 8] = av0;
        *(f16x8*)&As16[0][c1 * 512 + lane * 8] = av1;
        __syncthreads();
    }

    for (int ks = 0; ks < 8; ++ks) {
        const int cur = ks & 1;
        const int kse = (ks + stag) & 7;
        const bool notlast = (ks < 7);

        // issue next-step A loads FIRST: HBM latency hides under compute
        f32x4 n0a = {}, n0b = {}, n1a = {}, n1b = {};
        if (notlast) {
            const int ksn = (ks + 1 + stag) & 7;
            n0a = *(const f32x4*)(ab0 + ksn * 64);
            n0b = *(const f32x4*)(ab0 + ksn * 64 + 4);
            n1a = *(const f32x4*)(ab1 + ksn * 64);
            n1b = *(const f32x4*)(ab1 + ksn * 64 + 4);
        }

        // compute: B fragments direct from L2 (contiguous 1KB/instr),
        // A fragments lane-linear from LDS, 32 MFMA
#pragma unroll
        for (int kki = 0; kki < 2; ++kki) {
            f16x8 af[4];
#pragma unroll
            for (int mi = 0; mi < 4; ++mi)
                af[mi] = *(const f16x8*)&As16[cur][(kki * 4 + mi) * 512 + lane * 8];
#pragma unroll
            for (int ni = 0; ni < 4; ++ni) {
                const int c = (kse * 2 + kki) * 32 + nq + wave * 4 + ni;
                const f16x8 bf = *(const f16x8*)(P + (size_t)c * 512 + lane * 8);
#pragma unroll
                for (int mi = 0; mi < 4; ++mi)
                    acc[mi][ni] = __builtin_amdgcn_mfma_f32_16x16x32_f16(
                        af[mi], bf, acc[mi][ni], 0, 0, 0);
            }
        }

        // convert + stage next step into the other buffer
        if (notlast) {
            f16x8 av0, av1;
#pragma unroll
            for (int j = 0; j < 4; ++j) {
                av0[j] = (_Float16)(n0a[j] * 16.f); av0[j + 4] = (_Float16)(n0b[j] * 16.f);
                av1[j] = (_Float16)(n1a[j] * 16.f); av1[j + 4] = (_Float16)(n1b[j] * 16.f);
            }
            *(f16x8*)&As16[cur ^ 1][c0 * 512 + lane * 8] = av0;
            *(f16x8*)&As16[cur ^ 1][c1 * 512 + lane * 8] = av1;
        }
        __syncthreads();    // one barrier/step: next buffer ready, reads done
    }

    // epilogue: C/D layout col=lane&15, row=quad*4+reg
#pragma unroll
    for (int ni = 0; ni < 4; ++ni) {
        const int ncol = n0 + wave * 64 + ni * 16 + col_l;
#pragma unroll
        for (int mi = 0; mi < 4; ++mi) {
            const int mrow = m0 + mi * 16 + quad * 4;
#pragma unroll
            for (int r = 0; r < 4; ++r)
                C[(size_t)(mrow + r) * 512 + ncol] = (_Float16)acc[mi][ni][r];
        }
    }
}

// ---------------------------------------------------------------------------
// shared epilogue helpers
// ---------------------------------------------------------------------------
static __device__ __forceinline__ void emit_outputs(
    int row, int i1, int i2, float v1, float v2, float* out)
{
    out[OFF_S + row * 2 + 0] = v1;
    out[OFF_S + row * 2 + 1] = v2;
    out[OFF_N + row * 2 + 0] = (float)(i1 >> 2);
    out[OFF_N + row * 2 + 1] = (float)(i2 >> 2);
    out[OFF_L + row * 2 + 0] = (float)((i1 >> 1) & 1);
    out[OFF_L + row * 2 + 1] = (float)((i2 >> 1) & 1);
    out[OFF_R + row * 2 + 0] = (float)(i1 & 1);
    out[OFF_R + row * 2 + 1] = (float)(i2 & 1);
}

static __device__ __forceinline__ void gather_x(
    int row, int pos, int b, const int* top_z,
    const float* __restrict__ chart_h, uint16_t* __restrict__ X, int tid)
{
#pragma unroll
    for (int kq = 0; kq < 2; ++kq) {
        const int z = top_z[kq];
        const int n = z >> 2, lk = (z >> 1) & 1, rk = z & 1;
        const int lcell = level_off(n) + pos;
        const int rcell = level_off(15 - n) + pos + n + 1;
        const float* srcl = chart_h + ((size_t)(lk * B_DIM + b) * NCELLS + lcell) * SZ;
        const float* srcr = chart_h + ((size_t)(rk * B_DIM + b) * NCELLS + rcell) * SZ;
        uint16_t* dst = X + ((size_t)row * 2 + kq) * 1024;
        const int e = tid * 2;
        const float2 a = *(const float2*)(srcl + e);
        const float2 c = *(const float2*)(srcr + e);
        *(uint32_t*)(dst + e)       = (uint32_t)f2bf(a.x) | ((uint32_t)f2bf(a.y) << 16);
        *(uint32_t*)(dst + 512 + e) = (uint32_t)f2bf(c.x) | ((uint32_t)f2bf(c.y) << 16);
    }
}

// ---------------------------------------------------------------------------
// K2: cheap scores (lh f32 x T16 f16), top-3, near-tie flagging + candidate
// queue (ballot compaction). Clean rows emit outputs + gather X here.
// ---------------------------------------------------------------------------
__global__ __launch_bounds__(256)
void score_topk(const float* __restrict__ chart_h,   // f32
                const _Float16* __restrict__ T16,    // x1024
                const float* __restrict__ chart_s,
                uint32_t* __restrict__ items,        // queue entries (row<<6|z)
                int* __restrict__ rowbase,           // [1536]
                int* __restrict__ counter,           // 1 int, pre-zeroed
                int* __restrict__ flags,             // [1536]: nc (0 = clean)
                uint16_t* __restrict__ X,
                float* __restrict__ out)
{
    const int b   = blockIdx.x / L_DIM;
    const int pos = blockIdx.x % L_DIM;
    const int row = blockIdx.x;
    const int wave = threadIdx.x >> 6, lane = threadIdx.x & 63;

    __shared__ float s_sh[64];
    __shared__ int top_z[2];
    __shared__ int flag_sh;

#pragma unroll
    for (int ni = 0; ni < 4; ++ni) {
        const int n = wave * 4 + ni;
        const int lcell = level_off(n) + pos;
        const int rcell = level_off(15 - n) + pos + n + 1;

        const float* lp0 = chart_h + ((size_t)(0 * B_DIM + b) * NCELLS + lcell) * SZ + lane * 8;
        const float* lp1 = chart_h + ((size_t)(1 * B_DIM + b) * NCELLS + lcell) * SZ + lane * 8;
        const float4 l0a = *(const float4*)lp0, l0b = *(const float4*)(lp0 + 4);
        const float4 l1a = *(const float4*)lp1, l1b = *(const float4*)(lp1 + 4);
        const f16x8 t0 = *(const f16x8*)(T16 + ((size_t)(0 * B_DIM + b) * NCELLS + rcell) * SZ + lane * 8);
        const f16x8 t1 = *(const f16x8*)(T16 + ((size_t)(1 * B_DIM + b) * NCELLS + rcell) * SZ + lane * 8);

        float l0[8] = {l0a.x, l0a.y, l0a.z, l0a.w, l0b.x, l0b.y, l0b.z, l0b.w};
        float l1[8] = {l1a.x, l1a.y, l1a.z, l1a.w, l1b.x, l1b.y, l1b.z, l1b.w};

        float d00 = 0.f, d01 = 0.f, d10 = 0.f, d11 = 0.f;
#pragma unroll
        for (int j = 0; j < 8; ++j) {
            const float c0 = (float)t0[j], c1 = (float)t1[j];
            d00 += l0[j] * c0; d01 += l0[j] * c1;
            d10 += l1[j] * c0; d11 += l1[j] * c1;
        }
#pragma unroll
        for (int o = 32; o > 0; o >>= 1) {
            d00 += __shfl_down(d00, o);
            d01 += __shfl_down(d01, o);
            d10 += __shfl_down(d10, o);
            d11 += __shfl_down(d11, o);
        }
        if (lane == 0) {
            const float ls0 = chart_s[(size_t)(0 * B_DIM + b) * NCELLS + lcell];
            const float ls1 = chart_s[(size_t)(1 * B_DIM + b) * NCELLS + lcell];
            const float rs0 = chart_s[(size_t)(0 * B_DIM + b) * NCELLS + rcell];
            const float rs1 = chart_s[(size_t)(1 * B_DIM + b) * NCELLS + rcell];
            const float inv = 1.0f / 1024.0f;        // undo x1024 on T'
            s_sh[n * 4 + 0] = d00 * inv + ls0 + rs0;
            s_sh[n * 4 + 1] = d01 * inv + ls0 + rs1;
            s_sh[n * 4 + 2] = d10 * inv + ls1 + rs0;
            s_sh[n * 4 + 3] = d11 * inv + ls1 + rs1;
        }
    }
    __syncthreads();

    if (threadIdx.x < 64) {
        float v = s_sh[lane];
        if (lane == 2 || lane == 3) v = NEGF;        // penalty mask
        float v1 = v; int i1 = lane;
#pragma unroll
        for (int o = 32; o > 0; o >>= 1) {
            float ov = __shfl_down(v1, o);
            int   oi = __shfl_down(i1, o);
            if (ov > v1 || (ov == v1 && oi < i1)) { v1 = ov; i1 = oi; }
        }
        v1 = __shfl(v1, 0); i1 = __shfl(i1, 0);
        float v2 = (lane == i1) ? -3.4e38f : v; int i2 = lane;
#pragma unroll
        for (int o = 32; o > 0; o >>= 1) {
            float ov = __shfl_down(v2, o);
            int   oi = __shfl_down(i2, o);
            if (ov > v2 || (ov == v2 && oi < i2)) { v2 = ov; i2 = oi; }
        }
        v2 = __shfl(v2, 0); i2 = __shfl(i2, 0);
        float v3 = (lane == i1 || lane == i2) ? -3.4e38f : v;
#pragma unroll
        for (int o = 32; o > 0; o >>= 1) {
            const float ov = __shfl_down(v3, o);
            if (ov > v3) v3 = ov;
        }
        v3 = __shfl(v3, 0);

        const int f = (v1 - v2 < DELTA) || (v2 - v3 < DELTA);
        const bool cand = (v >= v2 - DELTA);
        const unsigned long long mask = __ballot(cand);
        const int nc_full = __popcll(mask);
        const int nc = nc_full < MAXC ? nc_full : MAXC;
        int base = 0;
        if (lane == 0) {
            flags[row] = f ? nc : 0;
            flag_sh = f;
            if (f) base = atomicAdd(counter, nc);
            rowbase[row] = base;
            top_z[0] = i1; top_z[1] = i2;
            if (!f) emit_outputs(row, i1, i2, v1, v2, out);
        }
        base = __shfl(base, 0);
        if (f && cand) {
            const int rank = __popcll(mask & ((1ull << lane) - 1ull));
            if (rank < MAXC) items[base + rank] = ((uint32_t)row << 6) | (uint32_t)lane;
        }
    }
    __syncthreads();

    if (!flag_sh)
        gather_x(row, pos, b, top_z, chart_h, X, threadIdx.x);
}

// ---------------------------------------------------------------------------
// K3a: exact f32 eval, block per ITEM PAIR (both items share the 1MB mat
// sweep). Waves split the e-range; lane owns rh[8*lane..+8) in regs.
// ---------------------------------------------------------------------------
__global__ __launch_bounds__(256)
void refine_eval(const float* __restrict__ chart_h,
                 const float* __restrict__ chart_s,
                 const float* __restrict__ mat,
                 const uint32_t* __restrict__ items,
                 const int* __restrict__ counter,
                 float* __restrict__ exval)
{
    const int total = *counter;
    const int t = threadIdx.x;
    const int wave = t >> 6, lane = t & 63;

    __shared__ float lh_sh[2][512];
    __shared__ float psum[2][4];

    for (int p = blockIdx.x; 2 * p < total; p += gridDim.x) {
        const int it0 = 2 * p;
        const int it1v = (2 * p + 1 < total);
        const uint32_t item0 = items[it0];
        const uint32_t item1 = it1v ? items[it0 + 1] : item0;

        int rowA = item0 >> 6, zA = item0 & 63;
        int bA = rowA / L_DIM, posA = rowA % L_DIM;
        int nA = zA >> 2, lkA = (zA >> 1) & 1, rkA = zA & 1;
        int lcA = level_off(nA) + posA, rcA = level_off(15 - nA) + posA + nA + 1;
        int rowB = item1 >> 6, zB = item1 & 63;
        int bB = rowB / L_DIM, posB = rowB % L_DIM;
        int nB = zB >> 2, lkB = (zB >> 1) & 1, rkB = zB & 1;
        int lcB = level_off(nB) + posB, rcB = level_off(15 - nB) + posB + nB + 1;

        const float* lhA = chart_h + ((size_t)(lkA * B_DIM + bA) * NCELLS + lcA) * SZ;
        const float* rhA = chart_h + ((size_t)(rkA * B_DIM + bA) * NCELLS + rcA) * SZ;
        const float* lhB = chart_h + ((size_t)(lkB * B_DIM + bB) * NCELLS + lcB) * SZ;
        const float* rhB = chart_h + ((size_t)(rkB * B_DIM + bB) * NCELLS + rcB) * SZ;

        __syncthreads();
        lh_sh[0][t] = lhA[t]; lh_sh[0][t + 256] = lhA[t + 256];
        lh_sh[1][t] = lhB[t]; lh_sh[1][t + 256] = lhB[t + 256];
        const float4 rA0 = *(const float4*)(rhA + lane * 8);
        const float4 rA1 = *(const float4*)(rhA + lane * 8 + 4);
        const float4 rB0 = *(const float4*)(rhB + lane * 8);
        const float4 rB1 = *(const float4*)(rhB + lane * 8 + 4);
        __syncthreads();

        const float* mb = mat + (size_t)(wave * 128) * 512 + lane * 8;
        float a00 = 0.f, a01 = 0.f, b00 = 0.f, b01 = 0.f;
        for (int e = 0; e < 128; e += 2) {
            const float4 m0 = *(const float4*)(mb + (size_t)(e + 0) * 512);
            const float4 m1 = *(const float4*)(mb + (size_t)(e + 0) * 512 + 4);
            const float4 m2 = *(const float4*)(mb + (size_t)(e + 1) * 512);
            const float4 m3 = *(const float4*)(mb + (size_t)(e + 1) * 512 + 4);
            const int eg = wave * 128 + e;
            const float lA0 = lh_sh[0][eg],     lB0 = lh_sh[1][eg];
            const float lA1 = lh_sh[0][eg + 1], lB1 = lh_sh[1][eg + 1];
            const float dA0 = m0.x*rA0.x + m0.y*rA0.y + m0.z*rA0.z + m0.w*rA0.w
                            + m1.x*rA1.x + m1.y*rA1.y + m1.z*rA1.z + m1.w*rA1.w;
            const float dB0 = m0.x*rB0.x + m0.y*rB0.y + m0.z*rB0.z + m0.w*rB0.w
                            + m1.x*rB1.x + m1.y*rB1.y + m1.z*rB1.z + m1.w*rB1.w;
            const float dA1 = m2.x*rA0.x + m2.y*rA0.y + m2.z*rA0.z + m2.w*rA0.w
                            + m3.x*rA1.x + m3.y*rA1.y + m3.z*rA1.z + m3.w*rA1.w;
            const float dB1 = m2.x*rB0.x + m2.y*rB0.y + m2.z*rB0.z + m2.w*rB0.w
                            + m3.x*rB1.x + m3.y*rB1.y + m3.z*rB1.z + m3.w*rB1.w;
            a00 += lA0 * dA0; a01 += lA1 * dA1;
            b00 += lB0 * dB0; b01 += lB1 * dB1;
        }
        float sA = a00 + a01, sB = b00 + b01;
#pragma unroll
        for (int o = 32; o > 0; o >>= 1) {
            sA += __shfl_down(sA, o);
            sB += __shfl_down(sB, o);
        }
        if (lane == 0) { psum[0][wave] = sA; psum[1][wave] = sB; }
        __syncthreads();
        if (t == 0) {
            const float lsA = chart_s[(size_t)(lkA * B_DIM + bA) * NCELLS + lcA];
            const float rsA = chart_s[(size_t)(rkA * B_DIM + bA) * NCELLS + rcA];
            exval[it0] = psum[0][0] + psum[0][1] + psum[0][2] + psum[0][3] + lsA + rsA;
            if (it1v) {
                const float lsB = chart_s[(size_t)(lkB * B_DIM + bB) * NCELLS + lcB];
                const float rsB = chart_s[(size_t)(rkB * B_DIM + bB) * NCELLS + rcB];
                exval[it0 + 1] = psum[1][0] + psum[1][1] + psum[1][2] + psum[1][3] + lsB + rsB;
            }
        }
    }
}

// ---------------------------------------------------------------------------
// K3b: per flagged row, pick exact top-2 (z-ascending list + strict '>'
// replicates jax lowest-index tie-break), emit outputs + gather X.
// ---------------------------------------------------------------------------
__global__ __launch_bounds__(256)
void refine_pick(const float* __restrict__ chart_h,
                 const uint32_t* __restrict__ items,
                 const int* __restrict__ rowbase,
                 const int* __restrict__ flags,
                 const float* __restrict__ exval,
                 uint16_t* __restrict__ X,
                 float* __restrict__ out)
{
    const int row = blockIdx.x;
    const int nc = flags[row];
    if (nc == 0) return;
    const int b = row / L_DIM, pos = row % L_DIM;
    const int t = threadIdx.x;

    __shared__ int top_z[2];

    if (t == 0) {
        const int base = rowbase[row];
        float v1 = -3.4e38f; int c1 = -1;
        for (int c = 0; c < nc; ++c) {
            const float v = exval[base + c];
            if (v > v1) { v1 = v; c1 = c; }
        }
        float v2 = -3.4e38f; int c2 = -1;
        for (int c = 0; c < nc; ++c) {
            if (c == c1) continue;
            const float v = exval[base + c];
            if (v > v2) { v2 = v; c2 = c; }
        }
        const int i1 = (int)(items[base + c1] & 63u);
        const int i2 = (int)(items[base + c2] & 63u);
        top_z[0] = i1; top_z[1] = i2;
        emit_outputs(row, i1, i2, v1, v2, out);
    }
    __syncthreads();
    gather_x(row, pos, b, top_z, chart_h, X, t);
}

// ---------------------------------------------------------------------------
// transpose_wc: WcT[o][i] = bf16(Wc[i][o])
// ---------------------------------------------------------------------------
__global__ __launch_bounds__(256)
void transpose_wc(const float* __restrict__ Wc, uint16_t* __restrict__ WcT)
{
    __shared__ float tbuf[64][65];
    const int i0 = blockIdx.x * 64;
    const int o0 = blockIdx.y * 64;
    const int c = threadIdx.x & 63, r4 = threadIdx.x >> 6;
    for (int rr = r4; rr < 64; rr += 4)
        tbuf[rr][c] = Wc[(size_t)(i0 + rr) * 512 + o0 + c];
    __syncthreads();
    for (int rr = r4; rr < 64; rr += 4)
        WcT[(size_t)(o0 + rr) * 1024 + i0 + c] = f2bf(tbuf[c][rr]);
}

// ---------------------------------------------------------------------------
// K4: H = tanh(X @ WcT^T + bc)  (bf16 in, f32 out)
// ---------------------------------------------------------------------------
typedef __bf16 bf16x8 __attribute__((ext_vector_type(8)));

__global__ __launch_bounds__(256, 2)
void gemm_compose(const uint16_t* __restrict__ A,
                  const uint16_t* __restrict__ Bm,
                  const float* __restrict__ bias,
                  float* __restrict__ C,
                  int M, int Nn, int Kk)
{
    __shared__ uint16_t As[128 * 64];
    __shared__ uint16_t Bs[128 * 64];

    const int tid  = threadIdx.x;
    const int wave = tid >> 6, lane = tid & 63;
    const int m0 = blockIdx.x * 128, n0 = blockIdx.y * 128;
    const int wm = (wave & 1) * 64, wn = (wave >> 1) * 64;
    const int col_l = lane & 15, quad = lane >> 4;
    const int lrow = lane >> 3;
    const int lcol = (lane & 7) * 8;

    f32x4 acc[4][4];
#pragma unroll
    for (int i = 0; i < 4; ++i)
#pragma unroll
        for (int j = 0; j < 4; ++j) acc[i][j] = (f32x4){0.f, 0.f, 0.f, 0.f};

    for (int k0 = 0; k0 < Kk; k0 += 64) {
        __syncthreads();
#pragma unroll
        for (int i = 0; i < 4; ++i) {
            const int q = wave * 4 + i;
            const int r = q * 8 + lrow;
            GLD16(A  + (size_t)(m0 + r) * Kk + k0 + lcol, (char*)As + q * 1024);
            GLD16(Bm + (size_t)(n0 + r) * Kk + k0 + lcol, (char*)Bs + q * 1024);
        }
        __syncthreads();
#pragma unroll
        for (int kk = 0; kk < 64; kk += 32) {
            bf16x8 af[4], bfr[4];
#pragma unroll
            for (int mi = 0; mi < 4; ++mi)
                af[mi] = *(const bf16x8*)&As[(wm + mi * 16 + col_l) * 64 + kk + quad * 8];
#pragma unroll
            for (int ni = 0; ni < 4; ++ni)
                bfr[ni] = *(const bf16x8*)&Bs[(wn + ni * 16 + col_l) * 64 + kk + quad * 8];
#pragma unroll
            for (int mi = 0; mi < 4; ++mi)
#pragma unroll
                for (int ni = 0; ni < 4; ++ni)
                    acc[mi][ni] = __builtin_amdgcn_mfma_f32_16x16x32_bf16(
                        af[mi], bfr[ni], acc[mi][ni], 0, 0, 0);
        }
    }

#pragma unroll
    for (int ni = 0; ni < 4; ++ni) {
        const int ncol = n0 + wn + ni * 16 + col_l;
        const float bv = bias[ncol];
#pragma unroll
        for (int mi = 0; mi < 4; ++mi) {
            const int mrow = m0 + wm + mi * 16 + quad * 4;
#pragma unroll
            for (int r = 0; r < 4; ++r)
                C[(size_t)(mrow + r) * Nn + ncol] = tanhf(acc[mi][ni][r] + bv);
        }
    }
}

// ---------------------------------------------------------------------------
// K5: unit-normalize H rows -> topk_h
// ---------------------------------------------------------------------------
__global__ __launch_bounds__(256)
void norm_rows(const float* __restrict__ H, float* __restrict__ out)
{
    const int row = blockIdx.x;
    const float* h = H + (size_t)row * SZ;
    const int t = threadIdx.x;
    const int wave = t >> 6, lane = t & 63;
    const float a = h[t], c = h[t + 256];
    float ss = a * a + c * c;
#pragma unroll
    for (int o = 32; o > 0; o >>= 1) ss += __shfl_down(ss, o);
    __shared__ float wsum[4];
    if (lane == 0) wsum[wave] = ss;
    __syncthreads();
    const float inv = rsqrtf(wsum[0] + wsum[1] + wsum[2] + wsum[3]);
    out[(size_t)row * SZ + t]       = a * inv;
    out[(size_t)row * SZ + t + 256] = c * inv;
}

// ---------------------------------------------------------------------------
extern "C" void kernel_launch(void* const* d_in, const int* in_sizes, int n_in,
                              void* d_out, int out_size, void* d_ws, size_t ws_size,
                              hipStream_t stream)
{
    const float* chart_h = (const float*)d_in[0];
    const float* chart_s = (const float*)d_in[1];
    const float* mat = (const float*)d_in[4];
    const float* Wc  = (const float*)d_in[5];
    const float* bc  = (const float*)d_in[6];
    float* out = (float*)d_out;

    // workspace (peak ~66.5 MB; proven ws >= 125.8 MB):
    //   T16   f16 [57856][512] @ 0            (59,244,544)  alive K1->K2
    //   MAT16 f16 packed       @ 59,244,544   (   524,288)  dead after K1
    //   ITEMS u32[49152]       @ 59,768,832   (   196,608)
    //   EXVAL f32[49152]       @ 59,965,440   (   196,608)
    //   RBASE i32[1536]        @ 60,162,048   (     6,144)
    //   CNT   i32              @ 60,168,192   (       256)
    //   FLAGS i32[1536]        @ 60,168,448   (     6,144)
    //   X     bf16[3072][1024] @ 60,174,592   ( 6,291,456)
    //   WcT   bf16[512][1024]  @ 0            (reuses T16 region after K2)
    //   H     f32 [3072][512]  @ 1,048,576    (reuses T16 region after K2)
    char* ws = (char*)d_ws;
    _Float16* T16   = (_Float16*)ws;
    _Float16* MAT16 = (_Float16*)(ws + 59244544);
    uint32_t* ITEMS = (uint32_t*)(ws + 59768832);
    float*    EXVAL = (float*)(ws + 59965440);
    int*      RBASE = (int*)(ws + 60162048);
    int*      CNT   = (int*)(ws + 60168192);
    int*      FLAGS = (int*)(ws + 60168448);
    uint16_t* X     = (uint16_t*)(ws + 60174592);
    uint16_t* WcT   = (uint16_t*)ws;
    float*    H     = (float*)(ws + 1048576);

    hipMemsetAsync(CNT, 0, 4, stream);
    // P0: packed mat16 (fragment-chunk order, f16(64*mat))
    prep_mat<<<dim3(128), 256, 0, stream>>>(mat, MAT16);
    // K1: T' = f16(16*chart_h) @ mat^T; B direct from L2, A dbuf LDS
    gemm_fused<<<dim3(2, 904), 256, 0, stream>>>(chart_h, MAT16, T16);
    // K2: cheap scores + top3 + candidate queue; outputs + X for clean rows
    score_topk<<<dim3(B_DIM * L_DIM), 256, 0, stream>>>(chart_h, T16, chart_s,
                                                        ITEMS, RBASE, CNT, FLAGS, X, out);
    // (T16/MAT16 dead from here; WcT/H overlay T16 region)
    transpose_wc<<<dim3(16, 8), 256, 0, stream>>>(Wc, WcT);
    // K3a: exact eval, block per item pair (mat shared within pair)
    refine_eval<<<dim3(1024), 256, 0, stream>>>(chart_h, chart_s, mat, ITEMS, CNT, EXVAL);
    // K3b: per-row exact top-2 + outputs + X
    refine_pick<<<dim3(B_DIM * L_DIM), 256, 0, stream>>>(chart_h, ITEMS, RBASE, FLAGS,
                                                         EXVAL, X, out);
    // K4: H = tanh(X @ WcT^T + bc)
    gemm_compose<<<dim3(24, 4), 256, 0, stream>>>(X, WcT, bc, H, 3072, 512, 1024);
    // K5: topk_h = H / ||H||
    norm_rows<<<dim3(3072), 256, 0, stream>>>(H, out);
}